// Round 1
// baseline (202.376 us; speedup 1.0000x reference)
//
#include <hip/hip_runtime.h>

typedef __bf16 bf16;
typedef bf16 bf16x4 __attribute__((ext_vector_type(4)));
typedef bf16 bf16x8 __attribute__((ext_vector_type(8)));
typedef float f32x4 __attribute__((ext_vector_type(4)));

#define NB 4
#define NC 256
#define ND 32
#define NN 4096

// ---------------------------------------------------------------------------
// Kernel 0: convert Wf/Wg/Wh (fp32 [32][256]) into one bf16 stack [96][256].
// ---------------------------------------------------------------------------
__global__ __launch_bounds__(256) void k_wcvt(
    const float* __restrict__ Wf, const float* __restrict__ Wg,
    const float* __restrict__ Wh, bf16* __restrict__ Wstk)
{
    int e0 = (blockIdx.x * 256 + threadIdx.x) * 8;   // 12 blocks * 2048 = 24576
    int row = e0 >> 8;                               // 0..95
    int tensor = row >> 5;                           // 0 f, 1 g, 2 h
    const float* src = tensor == 0 ? Wf : tensor == 1 ? Wg : Wh;
    const float* sp = src + (row & 31) * NC + (e0 & 255);
    bf16x8 v;
    #pragma unroll
    for (int j = 0; j < 8; ++j) v[j] = (bf16)sp[j];
    *reinterpret_cast<bf16x8*>(Wstk + e0) = v;
}

// ---------------------------------------------------------------------------
// Kernel 1: f/g/h = W @ x  (1x1 convs). Outputs:
//   fT,gT : [B][N][D] bf16   (row n contiguous over d -> MFMA frags are 16B)
//   hM    : [B][D][N] bf16   (row d contiguous over n -> PV A-frags are 16B)
// ---------------------------------------------------------------------------
__global__ __launch_bounds__(256) void k_fgh(
    const float* __restrict__ x,
    const bf16* __restrict__ Wstk,
    const float* __restrict__ bfp, const float* __restrict__ bgp,
    const float* __restrict__ bhp,
    bf16* __restrict__ fT, bf16* __restrict__ gT, bf16* __restrict__ hM)
{
    __shared__ __align__(16) char xb[64 * 512];  // [n][c] bf16, XOR-swizzled
    const int b  = blockIdx.y;
    const int n0 = blockIdx.x * 64;
    const int t  = threadIdx.x;
    const int lane = t & 63;
    const int w  = t >> 6;
    const int l15 = lane & 15;
    const int l4  = lane >> 4;

    // stage x tile [256 c][64 n] -> LDS transposed [n][c] bf16 (swizzled)
    {
        const int nl  = t & 63;
        const int swz = (nl & 7) << 4;
        const int chi = (t >> 6) * 8;
        #pragma unroll
        for (int pass = 0; pass < 8; ++pass) {
            int c0 = pass * 32 + chi;
            const float* xp = x + ((size_t)b * NC + c0) * NN + n0 + nl;
            bf16x8 v;
            #pragma unroll
            for (int j = 0; j < 8; ++j) v[j] = (bf16)xp[(size_t)j * NN];
            *reinterpret_cast<bf16x8*>(&xb[nl * 512 + ((c0 * 2) ^ swz)]) = v;
        }
    }
    __syncthreads();

    const int ncol = w * 16 + l15;       // wave owns 16-col n strip
    const int nswz = (ncol & 7) << 4;
    const int n    = n0 + ncol;
    const int dsub = l4 * 4;

    #pragma unroll
    for (int rt = 0; rt < 6; ++rt) {     // 6 row-tiles of 16 over [f;g;h]=96 rows
        int tensor = rt >> 1;
        int d0 = (rt & 1) * 16;
        f32x4 acc = {0.f, 0.f, 0.f, 0.f};
        #pragma unroll
        for (int kc = 0; kc < 8; ++kc) { // K = 256 in chunks of 32
            bf16x8 a = *reinterpret_cast<const bf16x8*>(
                Wstk + (rt * 16 + l15) * NC + kc * 32 + l4 * 8);
            bf16x8 bb = *reinterpret_cast<const bf16x8*>(
                &xb[ncol * 512 + ((kc * 64 + l4 * 16) ^ nswz)]);
            acc = __builtin_amdgcn_mfma_f32_16x16x32_bf16(a, bb, acc, 0, 0, 0);
        }
        const float* bsel = tensor == 0 ? bfp : tensor == 1 ? bgp : bhp;
        int dbase = d0 + dsub;
        if (tensor < 2) {
            bf16x4 vv;
            #pragma unroll
            for (int r = 0; r < 4; ++r) vv[r] = (bf16)(acc[r] + bsel[dbase + r]);
            bf16* dst = (tensor == 0 ? fT : gT) + ((size_t)b * NN + n) * ND + dbase;
            *reinterpret_cast<bf16x4*>(dst) = vv;
        } else {
            #pragma unroll
            for (int r = 0; r < 4; ++r)
                hM[((size_t)b * ND + dbase + r) * NN + n] =
                    (bf16)(acc[r] + bsel[dbase + r]);
        }
    }
}

// ---------------------------------------------------------------------------
// Kernel 2: L[n] = sum_m exp(S[n,m]), then scale h[:,n] *= 1/L[n] in place.
// (No max-subtraction needed: |S| <~ 12, exp fits fp32 comfortably.)
// ---------------------------------------------------------------------------
__global__ __launch_bounds__(256) void k_rowsum_scaleh(
    const bf16* __restrict__ fT, const bf16* __restrict__ gT,
    bf16* __restrict__ hM)
{
    __shared__ float rls[64];
    const int b  = blockIdx.y;
    const int nb = blockIdx.x * 64;
    const int t  = threadIdx.x;
    const int lane = t & 63;
    const int w  = t >> 6;               // wave owns n rows nb+w*16 .. +16
    const int l15 = lane & 15;
    const int l4  = lane >> 4;

    bf16x8 a = *reinterpret_cast<const bf16x8*>(
        fT + ((size_t)b * NN + nb + w * 16 + l15) * ND + l4 * 8);
    float sum0 = 0.f, sum1 = 0.f, sum2 = 0.f, sum3 = 0.f;
    const bf16* gp = gT + (size_t)b * NN * ND + (size_t)l15 * ND + l4 * 8;
    for (int m = 0; m < NN; m += 32) {
        bf16x8 b0 = *reinterpret_cast<const bf16x8*>(gp + (size_t)m * ND);
        bf16x8 b1 = *reinterpret_cast<const bf16x8*>(gp + (size_t)(m + 16) * ND);
        f32x4 z = {0.f, 0.f, 0.f, 0.f};
        f32x4 s0 = __builtin_amdgcn_mfma_f32_16x16x32_bf16(a, b0, z, 0, 0, 0);
        f32x4 s1 = __builtin_amdgcn_mfma_f32_16x16x32_bf16(a, b1, z, 0, 0, 0);
        sum0 += __expf(s0[0]) + __expf(s1[0]);
        sum1 += __expf(s0[1]) + __expf(s1[1]);
        sum2 += __expf(s0[2]) + __expf(s1[2]);
        sum3 += __expf(s0[3]) + __expf(s1[3]);
    }
    float sv[4] = {sum0, sum1, sum2, sum3};
    #pragma unroll
    for (int r = 0; r < 4; ++r) {        // reduce across the 16 lanes of a row
        float v = sv[r];
        v += __shfl_xor(v, 1);
        v += __shfl_xor(v, 2);
        v += __shfl_xor(v, 4);
        v += __shfl_xor(v, 8);
        sv[r] = v;
    }
    if (l15 == 0) {
        #pragma unroll
        for (int r = 0; r < 4; ++r)
            rls[w * 16 + l4 * 4 + r] = 1.0f / sv[r];
    }
    __syncthreads();
    {   // h[:, nb..nb+64] *= rls  (in place, bf16x8 vectorized)
        int d  = t >> 3;
        int ne = (t & 7) * 8;
        bf16* hp = hM + ((size_t)b * ND + d) * NN + nb + ne;
        bf16x8 hv = *reinterpret_cast<const bf16x8*>(hp);
        bf16x8 ho;
        #pragma unroll
        for (int j = 0; j < 8; ++j) ho[j] = (bf16)((float)hv[j] * rls[ne + j]);
        *reinterpret_cast<bf16x8*>(hp) = ho;
    }
}

// ---------------------------------------------------------------------------
// Kernel 3: per (b, 64-col m-tile):  sa[d,m] = sum_n h'[d,n] * exp(S[n,m]),
// then out[c,m] = gamma * (Wv @ sa + bv).  Each wave owns a 16-col m-strip;
// P strips are wave-private (no barriers except shared f/h tile staging).
// ---------------------------------------------------------------------------
__global__ __launch_bounds__(256) void k_attn_out(
    const bf16* __restrict__ fT, const bf16* __restrict__ gT,
    const bf16* __restrict__ hM,
    const float* __restrict__ Wv, const float* __restrict__ bv,
    const float* __restrict__ gamma, float* __restrict__ out)
{
    __shared__ __align__(16) char fL[64 * 80];    // [n][d] bf16, rows padded to 80B
    __shared__ __align__(16) char hL[32 * 144];   // [d][n] bf16, rows padded to 144B
    __shared__ __align__(16) char Pl[4 * 2048];   // per-wave [16 m][64 n] bf16, swizzled
    __shared__ float sa_s[64 * 33];               // [m][d] fp32, padded

    const int b  = blockIdx.y;
    const int m0 = blockIdx.x * 64;
    const int t  = threadIdx.x;
    const int lane = t & 63;
    const int w  = t >> 6;
    const int l15 = lane & 15;
    const int l4  = lane >> 4;

    // g fragment for this wave's m-strip (loaded once, held in regs)
    bf16x8 gfrag = *reinterpret_cast<const bf16x8*>(
        gT + ((size_t)b * NN + m0 + w * 16 + l15) * ND + l4 * 8);

    f32x4 acc0 = {0.f, 0.f, 0.f, 0.f};   // sa rows 0..15
    f32x4 acc1 = {0.f, 0.f, 0.f, 0.f};   // sa rows 16..31

    char* Pw = &Pl[w * 2048];
    const int mswz = (l15 & 7) << 4;

    const int s_nl = t >> 2;             // staging: fT 4KB contiguous
    const int s_dl = (t & 3) * 8;
    const int s_d  = t >> 3;             // staging: hM 32 rows x 128B
    const int s_ne = (t & 7) * 8;
    const bf16* fsrc = fT + (size_t)b * NN * ND;
    const bf16* hsrc = hM + (size_t)b * ND * NN;

    for (int n1 = 0; n1 < NN; n1 += 64) {
        __syncthreads();
        *reinterpret_cast<bf16x8*>(&fL[s_nl * 80 + s_dl * 2]) =
            *reinterpret_cast<const bf16x8*>(fsrc + (size_t)(n1 + s_nl) * ND + s_dl);
        *reinterpret_cast<bf16x8*>(&hL[s_d * 144 + s_ne * 2]) =
            *reinterpret_cast<const bf16x8*>(hsrc + (size_t)s_d * NN + n1 + s_ne);
        __syncthreads();

        // S phase: 4 n-subtiles of 16; P = exp(S) in bf16 (1/L already in h)
        #pragma unroll
        for (int nt = 0; nt < 4; ++nt) {
            bf16x8 afrag = *reinterpret_cast<const bf16x8*>(
                &fL[(nt * 16 + l15) * 80 + l4 * 16]);
            f32x4 z = {0.f, 0.f, 0.f, 0.f};
            f32x4 s = __builtin_amdgcn_mfma_f32_16x16x32_bf16(afrag, gfrag, z, 0, 0, 0);
            bf16x4 p4;
            #pragma unroll
            for (int r = 0; r < 4; ++r) p4[r] = (bf16)__expf(s[r]);
            *reinterpret_cast<bf16x4*>(
                &Pw[l15 * 128 + ((nt * 32 + l4 * 8) ^ mswz)]) = p4;
        }
        // PV phase: sa += h' @ P   (K = 64 in 2 chunks of 32)
        #pragma unroll
        for (int kc = 0; kc < 2; ++kc) {
            bf16x8 pb = *reinterpret_cast<const bf16x8*>(
                &Pw[l15 * 128 + ((kc * 64 + l4 * 16) ^ mswz)]);
            bf16x8 h0 = *reinterpret_cast<const bf16x8*>(
                &hL[l15 * 144 + kc * 64 + l4 * 16]);
            acc0 = __builtin_amdgcn_mfma_f32_16x16x32_bf16(h0, pb, acc0, 0, 0, 0);
            bf16x8 h1 = *reinterpret_cast<const bf16x8*>(
                &hL[(16 + l15) * 144 + kc * 64 + l4 * 16]);
            acc1 = __builtin_amdgcn_mfma_f32_16x16x32_bf16(h1, pb, acc1, 0, 0, 0);
        }
    }

    // sa -> LDS (fp32)
    {
        int mloc = w * 16 + l15;
        #pragma unroll
        for (int r = 0; r < 4; ++r) {
            sa_s[mloc * 33 + l4 * 4 + r]      = acc0[r];
            sa_s[mloc * 33 + 16 + l4 * 4 + r] = acc1[r];
        }
    }
    __syncthreads();

    // output projection: out[c, m] = gamma * (Wv[c,:] . sa[:,m] + bv[c])
    {
        const int mloc = t & 63;
        float sav[32];
        #pragma unroll
        for (int d = 0; d < 32; ++d) sav[d] = sa_s[mloc * 33 + d];
        const float g0 = gamma[0];
        const int cbase = __builtin_amdgcn_readfirstlane((t >> 6) * 64);
        float* op = out + (size_t)b * NC * NN + m0 + mloc;
        for (int i = 0; i < 64; ++i) {
            int c = cbase + i;
            const float* wp = Wv + c * ND;
            float sum = bv[c];
            #pragma unroll
            for (int d = 0; d < 32; ++d) sum = fmaf(wp[d], sav[d], sum);
            op[(size_t)c * NN] = g0 * sum;
        }
    }
}

// ---------------------------------------------------------------------------
extern "C" void kernel_launch(void* const* d_in, const int* in_sizes, int n_in,
                              void* d_out, int out_size, void* d_ws, size_t ws_size,
                              hipStream_t stream)
{
    const float* x   = (const float*)d_in[0];
    const float* Wf  = (const float*)d_in[1];
    const float* bfp = (const float*)d_in[2];
    const float* Wg  = (const float*)d_in[3];
    const float* bgp = (const float*)d_in[4];
    const float* Wh  = (const float*)d_in[5];
    const float* bhp = (const float*)d_in[6];
    const float* Wv  = (const float*)d_in[7];
    const float* bv  = (const float*)d_in[8];
    const float* gm  = (const float*)d_in[9];
    float* out = (float*)d_out;

    char* ws = (char*)d_ws;
    bf16* Wstk = (bf16*)ws;                               // 49152 B
    bf16* fT   = (bf16*)(ws + 49152);                     // 1 MB
    bf16* gT   = (bf16*)(ws + 49152 + 1048576);           // 1 MB
    bf16* hM   = (bf16*)(ws + 49152 + 2097152);           // 1 MB

    k_wcvt<<<dim3(12), dim3(256), 0, stream>>>(Wf, Wg, Wh, Wstk);
    k_fgh<<<dim3(64, NB), dim3(256), 0, stream>>>(x, Wstk, bfp, bgp, bhp, fT, gT, hM);
    k_rowsum_scaleh<<<dim3(64, NB), dim3(256), 0, stream>>>(fT, gT, hM);
    k_attn_out<<<dim3(64, NB), dim3(256), 0, stream>>>(fT, gT, hM, Wv, bv, gm, out);
}

// Round 2
// 157.087 us; speedup vs baseline: 1.2883x; 1.2883x over previous
//
#include <hip/hip_runtime.h>

typedef __bf16 bf16;
typedef bf16 bf16x4 __attribute__((ext_vector_type(4)));
typedef bf16 bf16x8 __attribute__((ext_vector_type(8)));
typedef float f32x4 __attribute__((ext_vector_type(4)));

#define NB 4
#define NC 256
#define ND 32
#define NN 4096
#define NSPLIT 4   // attn kernel: n-loop split across blocks
#define MSPLIT 4   // rowsum kernel: m-loop split across blocks

// ---------------------------------------------------------------------------
// Kernel 0: convert Wf/Wg/Wh (fp32 [32][256]) into one bf16 stack [96][256].
// ---------------------------------------------------------------------------
__global__ __launch_bounds__(256) void k_wcvt(
    const float* __restrict__ Wf, const float* __restrict__ Wg,
    const float* __restrict__ Wh, bf16* __restrict__ Wstk)
{
    int e0 = (blockIdx.x * 256 + threadIdx.x) * 8;   // 12 blocks * 2048 = 24576
    int row = e0 >> 8;                               // 0..95
    int tensor = row >> 5;                           // 0 f, 1 g, 2 h
    const float* src = tensor == 0 ? Wf : tensor == 1 ? Wg : Wh;
    const float* sp = src + (row & 31) * NC + (e0 & 255);
    bf16x8 v;
    #pragma unroll
    for (int j = 0; j < 8; ++j) v[j] = (bf16)sp[j];
    *reinterpret_cast<bf16x8*>(Wstk + e0) = v;
}

// ---------------------------------------------------------------------------
// Kernel 1: f/g/h = W @ x  (1x1 convs), 8 waves/block. Outputs:
//   fT,gT : [B][N][D] bf16   (row n contiguous over d -> MFMA frags are 16B)
//   hM    : [B][D][N] bf16   (row d contiguous over n -> PV A-frags are 16B)
// ---------------------------------------------------------------------------
__global__ __launch_bounds__(512) void k_fgh(
    const float* __restrict__ x,
    const bf16* __restrict__ Wstk,
    const float* __restrict__ bfp, const float* __restrict__ bgp,
    const float* __restrict__ bhp,
    bf16* __restrict__ fT, bf16* __restrict__ gT, bf16* __restrict__ hM)
{
    __shared__ __align__(16) char xb[64 * 512];  // [n][c] bf16, XOR-swizzled
    const int b  = blockIdx.y;
    const int n0 = blockIdx.x * 64;
    const int t  = threadIdx.x;
    const int lane = t & 63;
    const int w  = t >> 6;               // 0..7
    const int l15 = lane & 15;
    const int l4  = lane >> 4;

    // stage x tile [256 c][64 n] -> LDS transposed [n][c] bf16 (swizzled)
    {
        const int nl  = t & 63;
        const int swz = (nl & 7) << 4;
        const int chi = (t >> 6) * 8;    // 0..56 step 8
        #pragma unroll
        for (int pass = 0; pass < 4; ++pass) {
            int c0 = pass * 64 + chi;
            const float* xp = x + ((size_t)b * NC + c0) * NN + n0 + nl;
            bf16x8 v;
            #pragma unroll
            for (int j = 0; j < 8; ++j) v[j] = (bf16)xp[(size_t)j * NN];
            *reinterpret_cast<bf16x8*>(&xb[nl * 512 + ((c0 * 2) ^ swz)]) = v;
        }
    }
    __syncthreads();

    const int ncol = (w & 3) * 16 + l15; // 4 n-strips of 16
    const int nswz = (ncol & 7) << 4;
    const int n    = n0 + ncol;
    const int dsub = l4 * 4;
    const int rtb  = (w >> 2) * 3;       // waves 0-3: rt 0..2, waves 4-7: rt 3..5

    #pragma unroll
    for (int rr = 0; rr < 3; ++rr) {
        int rt = rtb + rr;
        int tensor = rt >> 1;
        int d0 = (rt & 1) * 16;
        f32x4 acc = {0.f, 0.f, 0.f, 0.f};
        #pragma unroll
        for (int kc = 0; kc < 8; ++kc) { // K = 256 in chunks of 32
            bf16x8 a = *reinterpret_cast<const bf16x8*>(
                Wstk + (rt * 16 + l15) * NC + kc * 32 + l4 * 8);
            bf16x8 bb = *reinterpret_cast<const bf16x8*>(
                &xb[ncol * 512 + ((kc * 64 + l4 * 16) ^ nswz)]);
            acc = __builtin_amdgcn_mfma_f32_16x16x32_bf16(a, bb, acc, 0, 0, 0);
        }
        const float* bsel = tensor == 0 ? bfp : tensor == 1 ? bgp : bhp;
        int dbase = d0 + dsub;
        if (tensor < 2) {
            bf16x4 vv;
            #pragma unroll
            for (int r = 0; r < 4; ++r) vv[r] = (bf16)(acc[r] + bsel[dbase + r]);
            bf16* dst = (tensor == 0 ? fT : gT) + ((size_t)b * NN + n) * ND + dbase;
            *reinterpret_cast<bf16x4*>(dst) = vv;
        } else {
            #pragma unroll
            for (int r = 0; r < 4; ++r)
                hM[((size_t)b * ND + dbase + r) * NN + n] =
                    (bf16)(acc[r] + bsel[dbase + r]);
        }
    }
}

// ---------------------------------------------------------------------------
// Kernel 2: partial L[n] = sum over an m-chunk of exp(S[n,m]).
// Grid (n-tile, m-split, b); no max-subtraction needed (|S| <~ 12).
// ---------------------------------------------------------------------------
__global__ __launch_bounds__(256) void k_rowsum(
    const bf16* __restrict__ fT, const bf16* __restrict__ gT,
    float* __restrict__ Lpart)
{
    const int b  = blockIdx.z;
    const int ms = blockIdx.y;
    const int nb = blockIdx.x * 64;
    const int t  = threadIdx.x;
    const int lane = t & 63;
    const int w  = t >> 6;               // wave owns n rows nb+w*16 .. +16
    const int l15 = lane & 15;
    const int l4  = lane >> 4;

    bf16x8 a = *reinterpret_cast<const bf16x8*>(
        fT + ((size_t)b * NN + nb + w * 16 + l15) * ND + l4 * 8);
    float sum0 = 0.f, sum1 = 0.f, sum2 = 0.f, sum3 = 0.f;
    const bf16* gp = gT + (size_t)b * NN * ND
                   + ((size_t)ms * (NN / MSPLIT) + l15) * ND + l4 * 8;
    #pragma unroll 4
    for (int m = 0; m < NN / MSPLIT; m += 32) {
        bf16x8 b0 = *reinterpret_cast<const bf16x8*>(gp + (size_t)m * ND);
        bf16x8 b1 = *reinterpret_cast<const bf16x8*>(gp + (size_t)(m + 16) * ND);
        f32x4 z = {0.f, 0.f, 0.f, 0.f};
        f32x4 s0 = __builtin_amdgcn_mfma_f32_16x16x32_bf16(a, b0, z, 0, 0, 0);
        f32x4 s1 = __builtin_amdgcn_mfma_f32_16x16x32_bf16(a, b1, z, 0, 0, 0);
        sum0 += __expf(s0[0]) + __expf(s1[0]);
        sum1 += __expf(s0[1]) + __expf(s1[1]);
        sum2 += __expf(s0[2]) + __expf(s1[2]);
        sum3 += __expf(s0[3]) + __expf(s1[3]);
    }
    float sv[4] = {sum0, sum1, sum2, sum3};
    #pragma unroll
    for (int r = 0; r < 4; ++r) {        // reduce across the 16 lanes of a row
        float v = sv[r];
        v += __shfl_xor(v, 1);
        v += __shfl_xor(v, 2);
        v += __shfl_xor(v, 4);
        v += __shfl_xor(v, 8);
        sv[r] = v;
    }
    if (l15 == 0) {
        #pragma unroll
        for (int r = 0; r < 4; ++r)
            Lpart[((size_t)ms * NB + b) * NN + nb + w * 16 + l4 * 4 + r] = sv[r];
    }
}

// ---------------------------------------------------------------------------
// Kernel 3: rl[n] = 1/sum(Lpart); h[:,n] *= rl[n] in place.
// ---------------------------------------------------------------------------
__global__ __launch_bounds__(256) void k_scaleh(
    const float* __restrict__ Lpart, bf16* __restrict__ hM)
{
    __shared__ float rls[64];
    const int b  = blockIdx.y;
    const int nb = blockIdx.x * 64;
    const int t  = threadIdx.x;
    if (t < 64) {
        float s = 0.f;
        #pragma unroll
        for (int ms = 0; ms < MSPLIT; ++ms)
            s += Lpart[((size_t)ms * NB + b) * NN + nb + t];
        rls[t] = 1.0f / s;
    }
    __syncthreads();
    int d  = t >> 3;
    int ne = (t & 7) * 8;
    bf16* hp = hM + ((size_t)b * ND + d) * NN + nb + ne;
    bf16x8 hv = *reinterpret_cast<const bf16x8*>(hp);
    bf16x8 ho;
    #pragma unroll
    for (int j = 0; j < 8; ++j) ho[j] = (bf16)((float)hv[j] * rls[ne + j]);
    *reinterpret_cast<bf16x8*>(hp) = ho;
}

// ---------------------------------------------------------------------------
// Kernel 4: partial sa[d,m] = sum over an n-chunk of h'[d,n]*exp(S[n,m]).
// Grid (m-tile, n-split, b). Each wave owns a 16-col m-strip; P strips are
// wave-private. Writes fp32 partials to saWS[split][b][m][d].
// ---------------------------------------------------------------------------
__global__ __launch_bounds__(256) void k_attn(
    const bf16* __restrict__ fT, const bf16* __restrict__ gT,
    const bf16* __restrict__ hM, float* __restrict__ saWS)
{
    __shared__ __align__(16) char fL[64 * 80];    // [n][d] bf16, rows padded to 80B
    __shared__ __align__(16) char hL[32 * 144];   // [d][n] bf16, rows padded to 144B
    __shared__ __align__(16) char Pl[4 * 2048];   // per-wave [16 m][64 n] bf16, swizzled

    const int b  = blockIdx.z;
    const int ns = blockIdx.y;
    const int m0 = blockIdx.x * 64;
    const int t  = threadIdx.x;
    const int lane = t & 63;
    const int w  = t >> 6;
    const int l15 = lane & 15;
    const int l4  = lane >> 4;

    bf16x8 gfrag = *reinterpret_cast<const bf16x8*>(
        gT + ((size_t)b * NN + m0 + w * 16 + l15) * ND + l4 * 8);

    f32x4 acc0 = {0.f, 0.f, 0.f, 0.f};   // sa rows d 0..15
    f32x4 acc1 = {0.f, 0.f, 0.f, 0.f};   // sa rows d 16..31

    char* Pw = &Pl[w * 2048];
    const int mswz = (l15 & 7) << 4;

    const int s_nl = t >> 2;             // staging: fT 4KB contiguous
    const int s_dl = (t & 3) * 8;
    const int s_d  = t >> 3;             // staging: hM 32 rows x 128B
    const int s_ne = (t & 7) * 8;
    const bf16* fsrc = fT + (size_t)b * NN * ND;
    const bf16* hsrc = hM + (size_t)b * ND * NN;

    const int nbeg = ns * (NN / NSPLIT);
    const int nend = nbeg + NN / NSPLIT;

    for (int n1 = nbeg; n1 < nend; n1 += 64) {
        __syncthreads();
        *reinterpret_cast<bf16x8*>(&fL[s_nl * 80 + s_dl * 2]) =
            *reinterpret_cast<const bf16x8*>(fsrc + (size_t)(n1 + s_nl) * ND + s_dl);
        *reinterpret_cast<bf16x8*>(&hL[s_d * 144 + s_ne * 2]) =
            *reinterpret_cast<const bf16x8*>(hsrc + (size_t)s_d * NN + n1 + s_ne);
        __syncthreads();

        // S phase: 4 n-subtiles of 16; P = exp(S) in bf16 (1/L already in h)
        #pragma unroll
        for (int nt = 0; nt < 4; ++nt) {
            bf16x8 afrag = *reinterpret_cast<const bf16x8*>(
                &fL[(nt * 16 + l15) * 80 + l4 * 16]);
            f32x4 z = {0.f, 0.f, 0.f, 0.f};
            f32x4 s = __builtin_amdgcn_mfma_f32_16x16x32_bf16(afrag, gfrag, z, 0, 0, 0);
            bf16x4 p4;
            #pragma unroll
            for (int r = 0; r < 4; ++r) p4[r] = (bf16)__expf(s[r]);
            *reinterpret_cast<bf16x4*>(
                &Pw[l15 * 128 + ((nt * 32 + l4 * 8) ^ mswz)]) = p4;
        }
        // PV phase: sa += h' @ P   (K = 64 in 2 chunks of 32)
        #pragma unroll
        for (int kc = 0; kc < 2; ++kc) {
            bf16x8 pb = *reinterpret_cast<const bf16x8*>(
                &Pw[l15 * 128 + ((kc * 64 + l4 * 16) ^ mswz)]);
            bf16x8 h0 = *reinterpret_cast<const bf16x8*>(
                &hL[l15 * 144 + kc * 64 + l4 * 16]);
            acc0 = __builtin_amdgcn_mfma_f32_16x16x32_bf16(h0, pb, acc0, 0, 0, 0);
            bf16x8 h1 = *reinterpret_cast<const bf16x8*>(
                &hL[(16 + l15) * 144 + kc * 64 + l4 * 16]);
            acc1 = __builtin_amdgcn_mfma_f32_16x16x32_bf16(h1, pb, acc1, 0, 0, 0);
        }
    }

    float* sp = saWS + (((size_t)ns * NB + b) * NN + m0 + w * 16 + l15) * ND;
    *reinterpret_cast<f32x4*>(sp + l4 * 4)      = acc0;
    *reinterpret_cast<f32x4*>(sp + 16 + l4 * 4) = acc1;
}

// ---------------------------------------------------------------------------
// Kernel 5: reduce sa partials, project: out[c,m] = gamma*(Wv[c,:].sa[:,m]+bv).
// 1024 threads: 16 waves; wave-uniform c-group -> scalar Wv loads.
// ---------------------------------------------------------------------------
__global__ __launch_bounds__(1024) void k_proj(
    const float* __restrict__ saWS,
    const float* __restrict__ Wv, const float* __restrict__ bv,
    const float* __restrict__ gamma, float* __restrict__ out)
{
    __shared__ float sa_s[64 * 33];
    const int b  = blockIdx.y;
    const int m0 = blockIdx.x * 64;
    const int t  = threadIdx.x;

    #pragma unroll
    for (int p = t; p < 64 * 32; p += 1024) {
        int m = p >> 5, d = p & 31;
        float s = 0.f;
        #pragma unroll
        for (int s4 = 0; s4 < NSPLIT; ++s4)
            s += saWS[(((size_t)s4 * NB + b) * NN + m0 + m) * ND + d];
        sa_s[m * 33 + d] = s;
    }
    __syncthreads();

    const int mloc = t & 63;
    const int cg   = t >> 6;             // wave-uniform
    float sav[32];
    #pragma unroll
    for (int d = 0; d < 32; ++d) sav[d] = sa_s[mloc * 33 + d];
    const float g0 = gamma[0];
    float* op = out + (size_t)b * NC * NN + m0 + mloc;
    #pragma unroll
    for (int i = 0; i < 16; ++i) {
        int c = cg * 16 + i;
        const float* wp = Wv + c * ND;
        float sum = bv[c];
        #pragma unroll
        for (int d = 0; d < 32; ++d) sum = fmaf(wp[d], sav[d], sum);
        op[(size_t)c * NN] = g0 * sum;
    }
}

// ---------------------------------------------------------------------------
extern "C" void kernel_launch(void* const* d_in, const int* in_sizes, int n_in,
                              void* d_out, int out_size, void* d_ws, size_t ws_size,
                              hipStream_t stream)
{
    const float* x   = (const float*)d_in[0];
    const float* Wf  = (const float*)d_in[1];
    const float* bfp = (const float*)d_in[2];
    const float* Wg  = (const float*)d_in[3];
    const float* bgp = (const float*)d_in[4];
    const float* Wh  = (const float*)d_in[5];
    const float* bhp = (const float*)d_in[6];
    const float* Wv  = (const float*)d_in[7];
    const float* bv  = (const float*)d_in[8];
    const float* gm  = (const float*)d_in[9];
    float* out = (float*)d_out;

    char* ws = (char*)d_ws;
    bf16*  Wstk  = (bf16*)ws;                                  // 48 KB
    bf16*  fT    = (bf16*)(ws + 49152);                        // 1 MB
    bf16*  gT    = (bf16*)(ws + 49152 + (1u << 20));           // 1 MB
    bf16*  hM    = (bf16*)(ws + 49152 + (2u << 20));           // 1 MB
    float* Lpart = (float*)(ws + 49152 + (3u << 20));          // 256 KB
    float* saWS  = (float*)(ws + 49152 + (3u << 20) + (256u << 10)); // 8 MB

    k_wcvt  <<<dim3(12),              dim3(256),  0, stream>>>(Wf, Wg, Wh, Wstk);
    k_fgh   <<<dim3(64, NB),          dim3(512),  0, stream>>>(x, Wstk, bfp, bgp, bhp, fT, gT, hM);
    k_rowsum<<<dim3(64, MSPLIT, NB),  dim3(256),  0, stream>>>(fT, gT, Lpart);
    k_scaleh<<<dim3(64, NB),          dim3(256),  0, stream>>>(Lpart, hM);
    k_attn  <<<dim3(64, NSPLIT, NB),  dim3(256),  0, stream>>>(fT, gT, hM, saWS);
    k_proj  <<<dim3(64, NB),          dim3(1024), 0, stream>>>(saWS, Wv, bv, gm, out);
}